// Round 3
// baseline (1021.906 us; speedup 1.0000x reference)
//
#include <hip/hip_runtime.h>

// ---------------------------------------------------------------------------
// Spiking net (LIF + WTA + STDP), MI355X implementation, round 3.
//
// Pipeline (all on `stream`, no grid-wide sync anywhere):
//   k_son   : I[t][h] = sum of w1[h][i] over inputs active at t (10-step
//             window of latency-coded spikes) — the entire layer-1 drive.
//   k_sim1  : ONE 256-thread block runs all 256 WTA steps for layer 1
//             (16 neurons/thread in registers); publishes result[t]=fire|gi
//             and per-h r1f/mask/relevance.
//   k_l2    : FUSED layer-2 sim + STDP2. Each block stages 4 w2 rows in LDS,
//             replays the 256 WTA results against the staged rows (LIF for
//             those 4 neurons), then computes w2_new for the rows from LDS.
//             Also writes error[n] and per-block error^2 partials.
//   k_stdp1 : w1_new = clip(stdp1[idx] + w1)  (+ error_scalar finisher).
//
// NOTE d_out layout is [error(8192) | scalar(1) | w1_new | w2_new]: w1_new
// and w2_new start at ODD float offsets -> never use float4 on them; outputs
// are written with scalar dword stores (inputs keep float4 loads).
//
// Scratch: I[t][h] (4 MB) lives inside d_out's w2_new region (dead until
// k_l2 overwrites it). Small per-neuron arrays + result[] in d_ws (~57 KB).
// ---------------------------------------------------------------------------

#define NH 4096
#define NI 8192
#define TT 256
#define HN_ ((size_t)NH * (size_t)NI)

#define B1 0.9f
#define B2 0.8f
#define D1C 0.001f
#define D2C 0.0005f
#define I1C 0.05f
#define I2C 0.02f
#define LATC 5.0f
#define TFC 256.0f

// ws layout (float/int indices into d_ws)
#define WS_RESULT 0              // int[256]
#define WS_R1F 256               // float[4096]
#define WS_MSK (256 + 4096)      // float[4096]
#define WS_REL (256 + 8192)      // float[4096]
#define WS_ERRP (256 + 12288)    // float[2048]
// total: 14592 * 4 = 58368 bytes

// d_out layout (float offsets)
#define OUT_SCALAR 8192
#define OUT_W1 8193
#define OUT_W2 (8193 + HN_)
#define OUT_SON (8704 + HN_)  // I[t][h]: TT*NH floats, inside w2_new region

// (max, min-index-on-tie, carried threshold) butterfly reduce across 64 lanes
__device__ __forceinline__ void reduce3(float& v, int& vi, float& vt) {
#pragma unroll
  for (int off = 32; off >= 1; off >>= 1) {
    float v2 = __shfl_xor(v, off);
    int i2 = __shfl_xor(vi, off);
    float t2 = __shfl_xor(vt, off);
    if (v2 > v || (v2 == v && i2 < vi)) { v = v2; vi = i2; vt = t2; }
  }
}

// ---------------------------------------------------------------------------
// son[t*NH + h] = sum_{tb=max(0,t-9)}^{t} bucket[tb],
// bucket[tb] = sum over inputs i with floor(256*image[i]) == tb of w1[h][i].
// One block per h, 64 lanes; deterministic accumulation order.
__global__ void __launch_bounds__(64) k_son(const float* __restrict__ image,
                                            const float* __restrict__ w1,
                                            float* __restrict__ son) {
  __shared__ float sp[TT * 64];  // 64 KB: per-lane private bucket columns
  __shared__ float btot[TT];
  const int lane = threadIdx.x;
  const int h = blockIdx.x;
  for (int t = 0; t < TT; ++t) sp[t * 64 + lane] = 0.f;
  const float4* row4 = reinterpret_cast<const float4*>(w1 + (size_t)h * NI);
  const float4* im4 = reinterpret_cast<const float4*>(image);
#define SON_ACC(W, U)                          \
  {                                            \
    int s_;                                    \
    s_ = (int)(TFC * (U).x);                   \
    if (s_ < TT) sp[s_ * 64 + lane] += (W).x;  \
    s_ = (int)(TFC * (U).y);                   \
    if (s_ < TT) sp[s_ * 64 + lane] += (W).y;  \
    s_ = (int)(TFC * (U).z);                   \
    if (s_ < TT) sp[s_ * 64 + lane] += (W).z;  \
    s_ = (int)(TFC * (U).w);                   \
    if (s_ < TT) sp[s_ * 64 + lane] += (W).w;  \
  }
  for (int base = 0; base < NI / 4; base += 256) {
    float4 wv0 = row4[base + lane];
    float4 wv1 = row4[base + 64 + lane];
    float4 wv2 = row4[base + 128 + lane];
    float4 wv3 = row4[base + 192 + lane];
    float4 u0 = im4[base + lane];
    float4 u1 = im4[base + 64 + lane];
    float4 u2 = im4[base + 128 + lane];
    float4 u3 = im4[base + 192 + lane];
    SON_ACC(wv0, u0);
    SON_ACC(wv1, u1);
    SON_ACC(wv2, u2);
    SON_ACC(wv3, u3);
  }
#undef SON_ACC
  __syncthreads();
  // bucket totals: lane handles t = k*64+lane, rotated read order (no bank
  // conflicts, deterministic per t)
  for (int k = 0; k < 4; ++k) {
    int t = k * 64 + lane;
    int base = t * 64;
    float acc = 0.f;
    for (int j = 0; j < 64; ++j) acc += sp[base + ((j + lane) & 63)];
    btot[t] = acc;
  }
  __syncthreads();
  // 10-step sliding window (ascending tb)
  for (int k = 0; k < 4; ++k) {
    int t = k * 64 + lane;
    int lo = t - 9;
    if (lo < 0) lo = 0;
    float s = 0.f;
    for (int tb = lo; tb <= t; ++tb) s += btot[tb];
    son[(size_t)t * NH + h] = s;
  }
}

// ---------------------------------------------------------------------------
// Layer 1: one block, 256 threads, h = j*256 + tid for j in [0,16).
__device__ __forceinline__ void l1_load(int t, int tid,
                                        const float* __restrict__ son,
                                        float (&buf)[16]) {
#pragma unroll
  for (int j = 0; j < 16; ++j) buf[j] = son[(size_t)t * NH + j * 256 + tid];
}

__device__ __forceinline__ void l1_step(int t, const float (&buf)[16],
                                        float (&mem)[16], float (&thr)[16],
                                        float (&r1)[16], unsigned& fmask,
                                        float (*pv)[4], float (*pt)[4],
                                        int (*pi)[4], int tid, int lane,
                                        int wid, int* __restrict__ resOut) {
  float v = -1.f;
  int vi = 0;
  float vt = 0.f;
#pragma unroll
  for (int j = 0; j < 16; ++j) {
    // two-rounding form (mul then add), matching the reference's separate ops
    mem[j] = __fadd_rn(__fmul_rn(B1, mem[j]), buf[j]);
    if (mem[j] > v) { v = mem[j]; vi = j * 256 + tid; vt = thr[j]; }
  }
  reduce3(v, vi, vt);
  const int par = t & 1;
  if (lane == 0) { pv[par][wid] = v; pi[par][wid] = vi; pt[par][wid] = vt; }
  __syncthreads();
  float gv = pv[par][0];
  int gi = pi[par][0];
  float gt = pt[par][0];
#pragma unroll
  for (int w = 1; w < 4; ++w) {
    float v2 = pv[par][w];
    int i2 = pi[par][w];
    float t2 = pt[par][w];
    if (v2 > gv || (v2 == gv && i2 < gi)) { gv = v2; gi = i2; gt = t2; }
  }
  const bool fire = gv > gt;
  if (tid == 0) resOut[t] = (fire ? 0x8000 : 0) | gi;
#pragma unroll
  for (int j = 0; j < 16; ++j) thr[j] = __fsub_rn(thr[j], D1C);  // thr - DECAY1
  if (fire && (gi & 255) == tid) {  // exactly one thread owns the winner
    const int wj = gi >> 8;
#pragma unroll
    for (int j = 0; j < 16; ++j) {
      if (wj == j) {
        thr[j] = __fadd_rn(thr[j], I1C);  // ... + INC1 (same assoc as ref)
        mem[j] = 0.f;                     // reset-to-zero
        fmask |= (1u << j);
        if (r1[j] == 0.f && t != 0) r1[j] = (float)t;
      }
    }
  }
}

__global__ void __launch_bounds__(256) k_sim1(const float* __restrict__ th1in,
                                              const float* __restrict__ son,
                                              int* __restrict__ resOut,
                                              float* __restrict__ wsF) {
  __shared__ float pv[2][4], pt[2][4];
  __shared__ int pi[2][4];
  const int tid = threadIdx.x, lane = tid & 63, wid = tid >> 6;
  float mem[16], thr[16], r1[16];
  unsigned fmask = 0;
#pragma unroll
  for (int j = 0; j < 16; ++j) {
    mem[j] = 0.f;
    r1[j] = 0.f;
    thr[j] = th1in[j * 256 + tid];
  }
  float A[16], Bb[16], Cc[16], Dd[16];
  l1_load(0, tid, son, A);
  l1_load(1, tid, son, Bb);
  l1_load(2, tid, son, Cc);
  l1_load(3, tid, son, Dd);
  for (int t = 0; t < TT; t += 4) {
    l1_step(t, A, mem, thr, r1, fmask, pv, pt, pi, tid, lane, wid, resOut);
    if (t + 4 < TT) l1_load(t + 4, tid, son, A);
    l1_step(t + 1, Bb, mem, thr, r1, fmask, pv, pt, pi, tid, lane, wid, resOut);
    if (t + 5 < TT) l1_load(t + 5, tid, son, Bb);
    l1_step(t + 2, Cc, mem, thr, r1, fmask, pv, pt, pi, tid, lane, wid, resOut);
    if (t + 6 < TT) l1_load(t + 6, tid, son, Cc);
    l1_step(t + 3, Dd, mem, thr, r1, fmask, pv, pt, pi, tid, lane, wid, resOut);
    if (t + 7 < TT) l1_load(t + 7, tid, son, Dd);
  }
#pragma unroll
  for (int j = 0; j < 16; ++j) {
    const int h = j * 256 + tid;
    float rr = (r1[j] == 0.f) ? TFC : r1[j];
    float m = ((fmask >> j) & 1u) ? 1.f : 0.f;
    wsF[WS_R1F + h] = rr;
    wsF[WS_MSK + h] = m;
    wsF[WS_REL + h] = ((TFC - rr) * m) / TFC;
  }
}

// ---------------------------------------------------------------------------
__device__ __forceinline__ float clamp01(float x) {
  return fminf(fmaxf(x, 0.f), 1.f);
}

__device__ __forceinline__ float stdp2_elem(float r2f, float rho, float r1f,
                                            float rel, float w,
                                            const float* t2) {
  float d = r2f - r1f;
  float v = (d + 257.0f) - 1.0f;  // (delta + OFFSET) - 1, reference assoc
  int idx = (int)v;               // trunc == astype(int32)
  idx = idx < 0 ? 0 : (idx > 512 ? 512 : idx);
  float dw = t2[idx] * (rho * rel);
  return clamp01(dw + w);
}

// FUSED layer-2 sim + STDP2. 2048 blocks x 256 threads; block owns rows
// n0..n0+3 of w2 ([NI, NH] row-major). Rows staged in LDS once (coalesced),
// sim reads the staged rows, STDP phase consumes them and writes w2_new.
__global__ void __launch_bounds__(256) k_l2(
    const float* __restrict__ image, const float* __restrict__ th2in,
    const float* __restrict__ w2, const float* __restrict__ tab,
    const int* __restrict__ res, const float* __restrict__ wsF,
    float* __restrict__ out, float* __restrict__ w2new,
    float* __restrict__ errp) {
  __shared__ float rows[4 * NH];  // 64 KB
  __shared__ float t2[513];
  __shared__ int sres[TT];
  __shared__ float sR2[4], sRho[4], sErr[4];
  const int tid = threadIdx.x;
  const int n0 = blockIdx.x * 4;

  sres[tid] = res[tid];
  for (int i = tid; i < 513; i += 256) t2[i] = tab[i];
  // stage 4 rows: 4096 float4 groups, 16 per thread, coalesced
#pragma unroll
  for (int i = 0; i < 16; ++i) {
    int f4 = i * 256 + tid;
    int r = f4 >> 10;
    int c4 = (f4 & 1023) << 2;
    float4 wv = *reinterpret_cast<const float4*>(w2 + ((size_t)(n0 + r) * NH + c4));
    *reinterpret_cast<float4*>(&rows[r * NH + c4]) = wv;
  }
  __syncthreads();

  // ---- sim phase: threads 0..3 replay their row's LIF ----
  if (tid < 4) {
    const int n = n0 + tid;
    float mem = 0.f, thr = th2in[n], r2 = 0.f;
    for (int t0 = 0; t0 < TT; t0 += 8) {
      int rr[8];
      float wv[8];
#pragma unroll
      for (int j = 0; j < 8; ++j) rr[j] = sres[t0 + j];
#pragma unroll
      for (int j = 0; j < 8; ++j)
        wv[j] = (rr[j] & 0x8000) ? rows[tid * NH + (rr[j] & 0xFFF)] : 0.f;
#pragma unroll
      for (int j = 0; j < 8; ++j) {
        const int t = t0 + j;
        mem = __fadd_rn(__fmul_rn(B2, mem), wv[j]);  // two-rounding form
        float sp = (mem > thr) ? 1.f : 0.f;
        if (sp != 0.f) {
          mem = __fsub_rn(mem, thr);  // reset-by-subtraction (pre-update thr)
          if (r2 == 0.f && t != 0) r2 = (float)t;
        }
        thr = __fsub_rn(thr, D2C);
        if (sp != 0.f) thr = __fadd_rn(thr, I2C);
      }
    }
    const float r2f = (r2 == 0.f) ? TFC : r2;
    const float it = TFC * image[n];
    const float err = (it - (r2f - LATC)) / TFC;
    out[n] = err;
    sR2[tid] = r2f;
    sRho[tid] = ((r2f - LATC) - it) / TFC + 0.15f;
    sErr[tid] = err * err;
  }
  __syncthreads();
  if (tid == 0)
    errp[blockIdx.x] = ((sErr[0] + sErr[1]) + sErr[2]) + sErr[3];  // fixed order

  // ---- STDP2 phase: all 256 threads, rows from LDS ----
#pragma unroll
  for (int i = 0; i < 16; ++i) {
    int f4 = i * 256 + tid;
    int r = f4 >> 10;
    int c4 = (f4 & 1023) << 2;
    float r2f = sR2[r];
    float rho = sRho[r];
    float4 wv = *reinterpret_cast<const float4*>(&rows[r * NH + c4]);
    float4 r1v = *reinterpret_cast<const float4*>(wsF + WS_R1F + c4);
    float4 rel = *reinterpret_cast<const float4*>(wsF + WS_REL + c4);
    float ox = stdp2_elem(r2f, rho, r1v.x, rel.x, wv.x, t2);
    float oy = stdp2_elem(r2f, rho, r1v.y, rel.y, wv.y, t2);
    float oz = stdp2_elem(r2f, rho, r1v.z, rel.z, wv.z, t2);
    float ow = stdp2_elem(r2f, rho, r1v.w, rel.w, wv.w, t2);
    // w2new base is at an ODD float offset in d_out -> scalar dword stores
    float* dst = w2new + ((size_t)(n0 + r) * NH + c4);
    dst[0] = ox;
    dst[1] = oy;
    dst[2] = oz;
    dst[3] = ow;
  }
}

// ---------------------------------------------------------------------------
__device__ __forceinline__ float stdp1_elem(float u, float w, float r1f,
                                            float m, const float* t1) {
  float it = TFC * u;
  float d = (r1f - it) * m;
  float v = (d + 257.0f) - 1.0f;
  int idx = (int)v;
  idx = idx < 0 ? 0 : (idx > 512 ? 512 : idx);
  return clamp01(t1[idx] + w);
}

__global__ void k_stdp1(const float* __restrict__ w1,
                        const float* __restrict__ image,
                        const float* __restrict__ tab,
                        const float* __restrict__ wsF,
                        float* __restrict__ w1new,
                        float* __restrict__ scalarOut) {
  __shared__ float t1[513];
  for (int i = threadIdx.x; i < 513; i += blockDim.x) t1[i] = tab[i];
  __syncthreads();
  if (blockIdx.x == 0 && threadIdx.x < 64) {
    // deterministic: lane k sums errp[32k..32k+31] in order, then butterfly
    float s = 0.f;
    const int base = threadIdx.x * 32;
    for (int k = 0; k < 32; ++k) s += wsF[WS_ERRP + base + k];
#pragma unroll
    for (int off = 32; off >= 1; off >>= 1) s += __shfl_xor(s, off);
    if (threadIdx.x == 0) *scalarOut = s;
  }
  const size_t total = HN_ / 4;
  const size_t stride = (size_t)gridDim.x * blockDim.x;
  for (size_t g = (size_t)blockIdx.x * blockDim.x + threadIdx.x; g < total;
       g += stride) {
    int h = (int)(g >> 11);  // NI/4 = 2048 float4-groups per row
    int n4 = (int)(g & 2047) * 4;
    float r1f = wsF[WS_R1F + h];
    float m = wsF[WS_MSK + h];
    float4 im = *reinterpret_cast<const float4*>(image + n4);
    float4 wv = *reinterpret_cast<const float4*>(w1 + ((size_t)h * NI + n4));
    float ox = stdp1_elem(im.x, wv.x, r1f, m, t1);
    float oy = stdp1_elem(im.y, wv.y, r1f, m, t1);
    float oz = stdp1_elem(im.z, wv.z, r1f, m, t1);
    float ow = stdp1_elem(im.w, wv.w, r1f, m, t1);
    // w1new base is at an ODD float offset in d_out -> scalar dword stores
    float* dst = w1new + ((size_t)h * NI + n4);
    dst[0] = ox;
    dst[1] = oy;
    dst[2] = oz;
    dst[3] = ow;
  }
}

// ---------------------------------------------------------------------------
extern "C" void kernel_launch(void* const* d_in, const int* in_sizes, int n_in,
                              void* d_out, int out_size, void* d_ws,
                              size_t ws_size, hipStream_t stream) {
  const float* image = (const float*)d_in[0];
  const float* w1 = (const float*)d_in[1];
  const float* w2 = (const float*)d_in[2];
  const float* th1 = (const float*)d_in[3];
  const float* th2 = (const float*)d_in[4];
  const float* stdp1t = (const float*)d_in[5];
  const float* stdp2t = (const float*)d_in[6];
  float* out = (float*)d_out;
  float* w1new = out + OUT_W1;
  float* w2new = out + OUT_W2;
  float* son = out + OUT_SON;  // scratch inside w2_new region (dead until k_l2)
  int* wsI = (int*)d_ws;
  float* wsF = (float*)d_ws;

  k_son<<<dim3(NH), dim3(64), 0, stream>>>(image, w1, son);
  k_sim1<<<dim3(1), dim3(256), 0, stream>>>(th1, son, wsI + WS_RESULT, wsF);
  k_l2<<<dim3(NI / 4), dim3(256), 0, stream>>>(image, th2, w2, stdp2t,
                                               wsI + WS_RESULT, wsF, out, w2new,
                                               wsF + WS_ERRP);
  k_stdp1<<<dim3(4096), dim3(256), 0, stream>>>(w1, image, stdp1t, wsF, w1new,
                                                out + OUT_SCALAR);
}